// Round 1
// baseline (1016.900 us; speedup 1.0000x reference)
//
#include <hip/hip_runtime.h>
#include <hip/hip_bf16.h>
#include <cstdint>
#include <math.h>

#define N_TOK 8192
#define D_DIM 1024
#define F_DIM 4096
#define NE 8
#define CAP 8192

typedef __attribute__((ext_vector_type(8))) short short8;
typedef __attribute__((ext_vector_type(4))) short short4v;
typedef __attribute__((ext_vector_type(4))) float f32x4;

__device__ __forceinline__ short f2bf(float f) {
  __bf16 b = (__bf16)f;
  return *(short*)&b;
}

__device__ __forceinline__ void gload_lds16(const void* g, void* l) {
  __builtin_amdgcn_global_load_lds(
      (const __attribute__((address_space(1))) uint32_t*)g,
      (__attribute__((address_space(3))) uint32_t*)l, 16, 0, 0);
}

// ---------------- gating: fp32 logits, top-2, renormalize, bucket scatter ----
__global__ __launch_bounds__(256) void gate_kernel(
    const float* __restrict__ X, const float* __restrict__ Wg,
    const float* __restrict__ bg, int* __restrict__ cnt,
    int* __restrict__ bucket, float* __restrict__ pairw)
{
  const int token = blockIdx.x;
  const int tid = threadIdx.x;
  const float* x = X + (size_t)token * D_DIM;
  float part[NE];
#pragma unroll
  for (int e = 0; e < NE; ++e) part[e] = 0.f;
  for (int d = tid; d < D_DIM; d += 256) {
    float xv = x[d];
#pragma unroll
    for (int e = 0; e < NE; ++e) part[e] = fmaf(xv, Wg[e * D_DIM + d], part[e]);
  }
#pragma unroll
  for (int e = 0; e < NE; ++e) {
#pragma unroll
    for (int off = 32; off > 0; off >>= 1) part[e] += __shfl_down(part[e], off);
  }
  __shared__ float wsum[4][NE];
  const int wave = tid >> 6;
  if ((tid & 63) == 0) {
#pragma unroll
    for (int e = 0; e < NE; ++e) wsum[wave][e] = part[e];
  }
  __syncthreads();
  if (tid == 0) {
    float lg[NE];
#pragma unroll
    for (int e = 0; e < NE; ++e)
      lg[e] = wsum[0][e] + wsum[1][e] + wsum[2][e] + wsum[3][e] + bg[e];
    int e0 = 0;
#pragma unroll
    for (int e = 1; e < NE; ++e) if (lg[e] > lg[e0]) e0 = e;     // jax tie-break: lower idx
    int e1 = (e0 == 0) ? 1 : 0;
#pragma unroll
    for (int e = 0; e < NE; ++e) if (e != e0 && lg[e] > lg[e1]) e1 = e;
    // softmax denominator cancels in top-2 renormalization:
    float p1 = expf(lg[e1] - lg[e0]);            // p0 = 1
    float inv = 1.f / (1.f + p1);
    pairw[token * 2]     = inv;
    pairw[token * 2 + 1] = p1 * inv;
    int pos0 = atomicAdd(&cnt[e0], 1);
    bucket[e0 * CAP + pos0] = token * 2;
    int pos1 = atomicAdd(&cnt[e1], 1);
    bucket[e1 * CAP + pos1] = token * 2 + 1;
  }
}

// ---------------- fp32 -> bf16 of hidden states -----------------------------
__global__ __launch_bounds__(256) void convert_x_kernel(
    const float* __restrict__ X, unsigned short* __restrict__ Xb)
{
  const int i = blockIdx.x * 256 + threadIdx.x;
  const float4 v = ((const float4*)X)[i];
  short4v o;
  o.x = f2bf(v.x); o.y = f2bf(v.y); o.z = f2bf(v.z); o.w = f2bf(v.w);
  ((short4v*)Xb)[i] = o;
}

// ---------------- per-expert transpose fp32 [R][C] -> bf16 [C][R] -----------
__global__ __launch_bounds__(256) void transpose_bf16_kernel(
    const float* __restrict__ src, unsigned short* __restrict__ dst, int R, int C)
{
  __shared__ float tile[32][33];
  const int ez = blockIdx.z;
  src += (size_t)ez * R * C;
  dst += (size_t)ez * R * C;
  const int c0 = blockIdx.x * 32, r0 = blockIdx.y * 32;
  const int tx = threadIdx.x, ty = threadIdx.y;
#pragma unroll
  for (int i = ty; i < 32; i += 8)
    tile[i][tx] = src[(size_t)(r0 + i) * C + c0 + tx];
  __syncthreads();
#pragma unroll
  for (int i = ty; i < 32; i += 8)
    dst[(size_t)(c0 + i) * R + r0 + tx] = (unsigned short)f2bf(tile[tx][i]);
}

// ---------------- grouped expert GEMM ---------------------------------------
// LAYER 1: hmid[pair] = gelu(X[token] @ W1[e] + b1[e])      (M=cnt_e, N=F, K=D)
// LAYER 2: out[token] += w * (hmid[pair] @ W2[e] + b2[e])   (M=cnt_e, N=D, K=F)
// A rows gathered via bucket; B = pre-transposed n-major weights.
template<int LAYER>
__global__ __launch_bounds__(256) void moe_gemm(
    const unsigned short* __restrict__ Abase,
    const unsigned short* __restrict__ Bt,
    const float* __restrict__ bias,
    const int* __restrict__ cnt,
    const int* __restrict__ bucket,
    const float* __restrict__ pairw,
    unsigned short* __restrict__ hmid,
    float* __restrict__ out)
{
  constexpr int BM = 128, BN = 128, BK = 64;
  constexpr int KDIM = (LAYER == 1) ? D_DIM : F_DIM;
  constexpr int NDIM = (LAYER == 1) ? F_DIM : D_DIM;
  constexpr int KT = KDIM / BK;

  const int e = blockIdx.z;
  const int cnt_e = cnt[e];
  const int mtile = blockIdx.y;
  if (mtile * BM >= cnt_e) return;
  const int ntile = blockIdx.x;

  __shared__ __align__(16) char Alds[BM * BK * 2];   // 16 KiB, row = 128 B
  __shared__ __align__(16) char Blds[BN * BK * 2];   // 16 KiB
  __shared__ int rowpair[BM];

  const int tid = threadIdx.x;
  const int lane = tid & 63;
  const int wave = tid >> 6;

  if (tid < BM) {
    int pos = mtile * BM + tid;
    rowpair[tid] = (pos < cnt_e) ? bucket[e * CAP + pos] : -1;
  }
  __syncthreads();

  // Staging plan: tile = 1024 chunks of 16 B; thread (wave,i,lane) owns chunk
  // ci = (i*4+wave)*64+lane -> LDS linear (global_load_lds dest). Source column
  // is pre-XOR-swizzled so swizzled ds_reads see the right data.
  const unsigned short* a_src[4];
  const unsigned short* b_src[4];
  char* a_dst[4];
  char* b_dst[4];
#pragma unroll
  for (int i = 0; i < 4; ++i) {
    int seg = i * 4 + wave;
    int ci = seg * 64 + lane;
    int r = ci >> 3, c = ci & 7;
    int sc = c ^ (r & 7);                      // inverse swizzle on source
    int pair = rowpair[r];
    int arow = (pair < 0) ? 0 : ((LAYER == 1) ? (pair >> 1) : pair);
    a_src[i] = Abase + (size_t)arow * KDIM + sc * 8;
    a_dst[i] = Alds + seg * 1024;
    int ng = ntile * BN + r;
    b_src[i] = Bt + (size_t)e * NDIM * KDIM + (size_t)ng * KDIM + sc * 8;
    b_dst[i] = Blds + seg * 1024;
  }

  f32x4 acc[4][4];
#pragma unroll
  for (int m = 0; m < 4; ++m)
#pragma unroll
    for (int n = 0; n < 4; ++n) acc[m][n] = (f32x4){0.f, 0.f, 0.f, 0.f};

  const int wm = wave >> 1, wn = wave & 1;
  const int l15 = lane & 15, lhi = lane >> 4;

  for (int kt = 0; kt < KT; ++kt) {
#pragma unroll
    for (int i = 0; i < 4; ++i) gload_lds16(a_src[i] + kt * BK, a_dst[i]);
#pragma unroll
    for (int i = 0; i < 4; ++i) gload_lds16(b_src[i] + kt * BK, b_dst[i]);
    asm volatile("s_waitcnt vmcnt(0)" ::: "memory");
    __syncthreads();
#pragma unroll
    for (int kk = 0; kk < 2; ++kk) {
      short8 af[4], bfr[4];
      const int c16 = kk * 4 + lhi;
#pragma unroll
      for (int m = 0; m < 4; ++m) {
        int row = wm * 64 + m * 16 + l15;
        af[m] = *(const short8*)(Alds + row * 128 + ((c16 ^ (row & 7)) * 16));
      }
#pragma unroll
      for (int n = 0; n < 4; ++n) {
        int row = wn * 64 + n * 16 + l15;
        bfr[n] = *(const short8*)(Blds + row * 128 + ((c16 ^ (row & 7)) * 16));
      }
#pragma unroll
      for (int m = 0; m < 4; ++m)
#pragma unroll
        for (int n = 0; n < 4; ++n)
          acc[m][n] = __builtin_amdgcn_mfma_f32_16x16x32_bf16(af[m], bfr[n], acc[m][n], 0, 0, 0);
    }
    __syncthreads();
  }

  // epilogue: C/D layout col = lane&15, row = (lane>>4)*4 + j
#pragma unroll
  for (int m = 0; m < 4; ++m) {
#pragma unroll
    for (int j = 0; j < 4; ++j) {
      const int row = wm * 64 + m * 16 + lhi * 4 + j;
      const int pair = rowpair[row];
      if (pair < 0) continue;
#pragma unroll
      for (int n = 0; n < 4; ++n) {
        const int col = ntile * BN + wn * 64 + n * 16 + l15;
        float v = acc[m][n][j] + bias[e * NDIM + col];
        if (LAYER == 1) {
          float g = 0.5f * v * (1.f + erff(v * 0.70710678118654752f));
          hmid[(size_t)pair * F_DIM + col] = (unsigned short)f2bf(g);
        } else {
          float y = v * pairw[pair];
          atomicAdd(out + ((size_t)(pair >> 1) * D_DIM + col), y);
        }
      }
    }
  }
}

// ---------------- launch ----------------------------------------------------
extern "C" void kernel_launch(void* const* d_in, const int* in_sizes, int n_in,
                              void* d_out, int out_size, void* d_ws, size_t ws_size,
                              hipStream_t stream)
{
  const float* X  = (const float*)d_in[0];
  const float* Wg = (const float*)d_in[1];
  const float* bg = (const float*)d_in[2];
  const float* W1 = (const float*)d_in[3];
  const float* b1 = (const float*)d_in[4];
  const float* W2 = (const float*)d_in[5];
  const float* b2 = (const float*)d_in[6];
  float* out = (float*)d_out;

  char* ws = (char*)d_ws;
  size_t off = 0;
  auto alloc = [&](size_t sz) {
    size_t o = off;
    off = (off + sz + 255) & ~(size_t)255;
    return o;
  };
  int*            cnt    = (int*)(ws + alloc(NE * sizeof(int)));
  int*            bucket = (int*)(ws + alloc((size_t)NE * CAP * sizeof(int)));
  float*          pairw  = (float*)(ws + alloc((size_t)N_TOK * 2 * sizeof(float)));
  unsigned short* Xb     = (unsigned short*)(ws + alloc((size_t)N_TOK * D_DIM * 2));
  unsigned short* W1t    = (unsigned short*)(ws + alloc((size_t)NE * D_DIM * F_DIM * 2));
  unsigned short* W2t    = (unsigned short*)(ws + alloc((size_t)NE * D_DIM * F_DIM * 2));
  unsigned short* hmid   = (unsigned short*)(ws + alloc((size_t)N_TOK * 2 * F_DIM * 2));

  hipMemsetAsync(cnt, 0, NE * sizeof(int), stream);
  hipMemsetAsync(out, 0, (size_t)out_size * sizeof(float), stream);

  convert_x_kernel<<<N_TOK * D_DIM / 4 / 256, 256, 0, stream>>>(X, Xb);
  transpose_bf16_kernel<<<dim3(F_DIM / 32, D_DIM / 32, NE), dim3(32, 8), 0, stream>>>(
      W1, W1t, D_DIM, F_DIM);
  transpose_bf16_kernel<<<dim3(D_DIM / 32, F_DIM / 32, NE), dim3(32, 8), 0, stream>>>(
      W2, W2t, F_DIM, D_DIM);
  gate_kernel<<<N_TOK, 256, 0, stream>>>(X, Wg, bg, cnt, bucket, pairw);
  moe_gemm<1><<<dim3(F_DIM / 128, N_TOK / 128, NE), 256, 0, stream>>>(
      Xb, W1t, b1, cnt, bucket, pairw, hmid, out);
  moe_gemm<2><<<dim3(D_DIM / 128, N_TOK / 128, NE), 256, 0, stream>>>(
      hmid, W2t, b2, cnt, bucket, pairw, hmid, out);
}

// Round 2
// 997.138 us; speedup vs baseline: 1.0198x; 1.0198x over previous
//
#include <hip/hip_runtime.h>
#include <hip/hip_bf16.h>
#include <cstdint>
#include <math.h>

#define N_TOK 8192
#define D_DIM 1024
#define F_DIM 4096
#define NE 8
#define CAP 8192

typedef __attribute__((ext_vector_type(8))) short short8;
typedef __attribute__((ext_vector_type(4))) short short4v;
typedef __attribute__((ext_vector_type(4))) float f32x4;

__device__ __forceinline__ short f2bf(float f) {
  __bf16 b = (__bf16)f;
  return *(short*)&b;
}

__device__ __forceinline__ void gload_lds16(const void* g, void* l) {
  __builtin_amdgcn_global_load_lds(
      (const __attribute__((address_space(1))) uint32_t*)g,
      (__attribute__((address_space(3))) uint32_t*)l, 16, 0, 0);
}

// ---------------- gating: fp32 logits, top-2, renormalize, bucket scatter ----
__global__ __launch_bounds__(256) void gate_kernel(
    const float* __restrict__ X, const float* __restrict__ Wg,
    const float* __restrict__ bg, int* __restrict__ cnt,
    int* __restrict__ bucket, float* __restrict__ pairw)
{
  const int token = blockIdx.x;
  const int tid = threadIdx.x;
  const float* x = X + (size_t)token * D_DIM;
  float part[NE];
#pragma unroll
  for (int e = 0; e < NE; ++e) part[e] = 0.f;
  for (int d = tid; d < D_DIM; d += 256) {
    float xv = x[d];
#pragma unroll
    for (int e = 0; e < NE; ++e) part[e] = fmaf(xv, Wg[e * D_DIM + d], part[e]);
  }
#pragma unroll
  for (int e = 0; e < NE; ++e) {
#pragma unroll
    for (int off = 32; off > 0; off >>= 1) part[e] += __shfl_down(part[e], off);
  }
  __shared__ float wsum[4][NE];
  const int wave = tid >> 6;
  if ((tid & 63) == 0) {
#pragma unroll
    for (int e = 0; e < NE; ++e) wsum[wave][e] = part[e];
  }
  __syncthreads();
  if (tid == 0) {
    float lg[NE];
#pragma unroll
    for (int e = 0; e < NE; ++e)
      lg[e] = wsum[0][e] + wsum[1][e] + wsum[2][e] + wsum[3][e] + bg[e];
    int e0 = 0;
#pragma unroll
    for (int e = 1; e < NE; ++e) if (lg[e] > lg[e0]) e0 = e;     // jax tie-break: lower idx
    int e1 = (e0 == 0) ? 1 : 0;
#pragma unroll
    for (int e = 0; e < NE; ++e) if (e != e0 && lg[e] > lg[e1]) e1 = e;
    // softmax denominator cancels in top-2 renormalization:
    float p1 = expf(lg[e1] - lg[e0]);            // p0 = 1
    float inv = 1.f / (1.f + p1);
    pairw[token * 2]     = inv;
    pairw[token * 2 + 1] = p1 * inv;
    int pos0 = atomicAdd(&cnt[e0], 1);
    bucket[e0 * CAP + pos0] = token * 2;
    int pos1 = atomicAdd(&cnt[e1], 1);
    bucket[e1 * CAP + pos1] = token * 2 + 1;
  }
}

// ---------------- fp32 -> bf16 of hidden states -----------------------------
__global__ __launch_bounds__(256) void convert_x_kernel(
    const float* __restrict__ X, unsigned short* __restrict__ Xb)
{
  const int i = blockIdx.x * 256 + threadIdx.x;
  const float4 v = ((const float4*)X)[i];
  short4v o;
  o.x = f2bf(v.x); o.y = f2bf(v.y); o.z = f2bf(v.z); o.w = f2bf(v.w);
  ((short4v*)Xb)[i] = o;
}

// ---------------- per-expert transpose fp32 [R][C] -> bf16 [C][R] -----------
__global__ __launch_bounds__(256) void transpose_bf16_kernel(
    const float* __restrict__ src, unsigned short* __restrict__ dst, int R, int C)
{
  __shared__ float tile[32][33];
  const int ez = blockIdx.z;
  src += (size_t)ez * R * C;
  dst += (size_t)ez * R * C;
  const int c0 = blockIdx.x * 32, r0 = blockIdx.y * 32;
  const int tx = threadIdx.x, ty = threadIdx.y;
#pragma unroll
  for (int i = ty; i < 32; i += 8)
    tile[i][tx] = src[(size_t)(r0 + i) * C + c0 + tx];
  __syncthreads();
#pragma unroll
  for (int i = ty; i < 32; i += 8)
    dst[(size_t)(c0 + i) * R + r0 + tx] = (unsigned short)f2bf(tile[tx][i]);
}

// ---------------- grouped expert GEMM, 256x256 tile, 2-phase dbuf -----------
// LAYER 1: hmid[pair] = gelu(X[token] @ W1[e] + b1[e])      (M=cnt_e, N=F, K=D)
// LAYER 2: out[token] += w * (hmid[pair] @ W2[e] + b2[e])   (M=cnt_e, N=D, K=F)
// A rows gathered via bucket; B = pre-transposed n-major bf16 weights.
// 8 waves (2M x 4N); per-wave output 128x64; acc[8][4] f32x4.
// LDS 129 KB -> 1 block/CU; latency hidden by prefetching K-tile t+1's
// global_load_lds before computing K-tile t (2-phase schedule, m248-style).
template<int LAYER>
__global__ __launch_bounds__(512, 2) void moe_gemm(
    const unsigned short* __restrict__ Abase,
    const unsigned short* __restrict__ Bt,
    const float* __restrict__ bias,
    const int* __restrict__ cnt,
    const int* __restrict__ bucket,
    const float* __restrict__ pairw,
    unsigned short* __restrict__ hmid,
    float* __restrict__ out)
{
  constexpr int BM = 256, BN = 256, BK = 64;
  constexpr int KDIM = (LAYER == 1) ? D_DIM : F_DIM;
  constexpr int NDIM = (LAYER == 1) ? F_DIM : D_DIM;
  constexpr int KT = KDIM / BK;
  constexpr int SLOT = BM * BK * 2;          // 32 KiB per buffer slot

  const int e = blockIdx.z;
  const int cnt_e = cnt[e];
  const int mtile = blockIdx.y;
  if (mtile * BM >= cnt_e) return;
  const int ntile = blockIdx.x;

  __shared__ __align__(16) char Alds[2][SLOT];   // 64 KiB
  __shared__ __align__(16) char Blds[2][SLOT];   // 64 KiB
  __shared__ int rowpair[BM];

  const int tid = threadIdx.x;
  const int lane = tid & 63;
  const int l15 = lane & 15, lhi = lane >> 4;
  const int wid = tid >> 6;
  const int wm = wid >> 2, wn = wid & 3;

  if (tid < BM) {
    int pos = mtile * BM + tid;
    rowpair[tid] = (pos < cnt_e) ? bucket[e * CAP + pos] : -1;
  }
  __syncthreads();

  // Staging plan: tile = 2048 chunks of 16 B; thread tid, load i owns chunk
  // ci = i*512 + tid -> LDS linear (global_load_lds dest = wave-uniform base +
  // lane*16). Source column is pre-XOR-swizzled so swizzled ds_reads see the
  // right data (both-sides-or-neither rule).
  const unsigned short* a_src[4];
  const unsigned short* b_src[4];
  int a_off[4], b_off[4];
#pragma unroll
  for (int i = 0; i < 4; ++i) {
    int ci = i * 512 + tid;
    int r = ci >> 3, c = ci & 7;
    int sc = c ^ (r & 7);                      // inverse swizzle on source
    int pair = rowpair[r];
    int arow = (pair < 0) ? 0 : ((LAYER == 1) ? (pair >> 1) : pair);
    a_src[i] = Abase + (size_t)arow * KDIM + sc * 8;
    a_off[i] = ci * 16;
    int ng = ntile * BN + r;
    b_src[i] = Bt + (size_t)e * NDIM * KDIM + (size_t)ng * KDIM + sc * 8;
    b_off[i] = ci * 16;
  }

  f32x4 acc[8][4];
#pragma unroll
  for (int m = 0; m < 8; ++m)
#pragma unroll
    for (int n = 0; n < 4; ++n) acc[m][n] = (f32x4){0.f, 0.f, 0.f, 0.f};

  // prologue: stage K-tile 0 into slot 0
#pragma unroll
  for (int i = 0; i < 4; ++i) gload_lds16(a_src[i], &Alds[0][0] + a_off[i]);
#pragma unroll
  for (int i = 0; i < 4; ++i) gload_lds16(b_src[i], &Blds[0][0] + b_off[i]);
  __syncthreads();                             // drains vmcnt(0)

  int cur = 0;
  for (int kt = 0; kt < KT; ++kt) {
    // phase A: issue next K-tile's loads into the other slot (overlaps MFMA)
    if (kt + 1 < KT) {
      const int nxt = cur ^ 1;
#pragma unroll
      for (int i = 0; i < 4; ++i)
        gload_lds16(a_src[i] + (kt + 1) * BK, &Alds[nxt][0] + a_off[i]);
#pragma unroll
      for (int i = 0; i < 4; ++i)
        gload_lds16(b_src[i] + (kt + 1) * BK, &Blds[nxt][0] + b_off[i]);
    }
    // phase B: compute current K-tile from LDS
#pragma unroll
    for (int kk = 0; kk < 2; ++kk) {
      const int c16 = kk * 4 + lhi;
      short8 bfr[4];
#pragma unroll
      for (int n = 0; n < 4; ++n) {
        int row = wn * 64 + n * 16 + l15;
        bfr[n] = *(const short8*)(&Blds[cur][0] + row * 128 + ((c16 ^ (row & 7)) * 16));
      }
#pragma unroll
      for (int m = 0; m < 8; ++m) {
        int row = wm * 128 + m * 16 + l15;
        short8 af = *(const short8*)(&Alds[cur][0] + row * 128 + ((c16 ^ (row & 7)) * 16));
#pragma unroll
        for (int n = 0; n < 4; ++n)
          acc[m][n] = __builtin_amdgcn_mfma_f32_16x16x32_bf16(af, bfr[n], acc[m][n], 0, 0, 0);
      }
    }
    __syncthreads();   // drains this iteration's prefetch + orders buffer reuse
    cur ^= 1;
  }

  // epilogue: C/D layout col = lane&15, row = (lane>>4)*4 + j
#pragma unroll
  for (int m = 0; m < 8; ++m) {
#pragma unroll
    for (int j = 0; j < 4; ++j) {
      const int row = wm * 128 + m * 16 + lhi * 4 + j;
      const int pair = rowpair[row];
      if (pair < 0) continue;
#pragma unroll
      for (int n = 0; n < 4; ++n) {
        const int col = ntile * BN + wn * 64 + n * 16 + l15;
        float v = acc[m][n][j] + bias[e * NDIM + col];
        if (LAYER == 1) {
          float g = 0.5f * v * (1.f + erff(v * 0.70710678118654752f));
          hmid[(size_t)pair * F_DIM + col] = (unsigned short)f2bf(g);
        } else {
          float y = v * pairw[pair];
          atomicAdd(out + ((size_t)(pair >> 1) * D_DIM + col), y);
        }
      }
    }
  }
}

// ---------------- launch ----------------------------------------------------
extern "C" void kernel_launch(void* const* d_in, const int* in_sizes, int n_in,
                              void* d_out, int out_size, void* d_ws, size_t ws_size,
                              hipStream_t stream)
{
  const float* X  = (const float*)d_in[0];
  const float* Wg = (const float*)d_in[1];
  const float* bg = (const float*)d_in[2];
  const float* W1 = (const float*)d_in[3];
  const float* b1 = (const float*)d_in[4];
  const float* W2 = (const float*)d_in[5];
  const float* b2 = (const float*)d_in[6];
  float* out = (float*)d_out;

  char* ws = (char*)d_ws;
  size_t off = 0;
  auto alloc = [&](size_t sz) {
    size_t o = off;
    off = (off + sz + 255) & ~(size_t)255;
    return o;
  };
  int*            cnt    = (int*)(ws + alloc(NE * sizeof(int)));
  int*            bucket = (int*)(ws + alloc((size_t)NE * CAP * sizeof(int)));
  float*          pairw  = (float*)(ws + alloc((size_t)N_TOK * 2 * sizeof(float)));
  unsigned short* Xb     = (unsigned short*)(ws + alloc((size_t)N_TOK * D_DIM * 2));
  unsigned short* W1t    = (unsigned short*)(ws + alloc((size_t)NE * D_DIM * F_DIM * 2));
  unsigned short* W2t    = (unsigned short*)(ws + alloc((size_t)NE * D_DIM * F_DIM * 2));
  unsigned short* hmid   = (unsigned short*)(ws + alloc((size_t)N_TOK * 2 * F_DIM * 2));

  hipMemsetAsync(cnt, 0, NE * sizeof(int), stream);
  hipMemsetAsync(out, 0, (size_t)out_size * sizeof(float), stream);

  convert_x_kernel<<<N_TOK * D_DIM / 4 / 256, 256, 0, stream>>>(X, Xb);
  transpose_bf16_kernel<<<dim3(F_DIM / 32, D_DIM / 32, NE), dim3(32, 8), 0, stream>>>(
      W1, W1t, D_DIM, F_DIM);
  transpose_bf16_kernel<<<dim3(D_DIM / 32, F_DIM / 32, NE), dim3(32, 8), 0, stream>>>(
      W2, W2t, F_DIM, D_DIM);
  gate_kernel<<<N_TOK, 256, 0, stream>>>(X, Wg, bg, cnt, bucket, pairw);
  moe_gemm<1><<<dim3(F_DIM / 256, N_TOK / 256, NE), 512, 0, stream>>>(
      Xb, W1t, b1, cnt, bucket, pairw, hmid, out);
  moe_gemm<2><<<dim3(D_DIM / 256, N_TOK / 256, NE), 512, 0, stream>>>(
      hmid, W2t, b2, cnt, bucket, pairw, hmid, out);
}

// Round 3
// 979.506 us; speedup vs baseline: 1.0382x; 1.0180x over previous
//
#include <hip/hip_runtime.h>
#include <hip/hip_bf16.h>
#include <cstdint>
#include <math.h>

#define N_TOK 8192
#define D_DIM 1024
#define F_DIM 4096
#define NE 8
#define CAP 8192

typedef __attribute__((ext_vector_type(8))) short short8;
typedef __attribute__((ext_vector_type(4))) short short4v;
typedef __attribute__((ext_vector_type(4))) float f32x4;

__device__ __forceinline__ short f2bf(float f) {
  __bf16 b = (__bf16)f;
  return *(short*)&b;
}

__device__ __forceinline__ void gload_lds16(const void* g, void* l) {
  __builtin_amdgcn_global_load_lds(
      (const __attribute__((address_space(1))) uint32_t*)g,
      (__attribute__((address_space(3))) uint32_t*)l, 16, 0, 0);
}

// ---------------- gating: fp32 logits, top-2, renormalize, bucket scatter ----
__global__ __launch_bounds__(256) void gate_kernel(
    const float* __restrict__ X, const float* __restrict__ Wg,
    const float* __restrict__ bg, int* __restrict__ cnt,
    int* __restrict__ bucket, float* __restrict__ pairw)
{
  const int token = blockIdx.x;
  const int tid = threadIdx.x;
  const float* x = X + (size_t)token * D_DIM;
  float part[NE];
#pragma unroll
  for (int e = 0; e < NE; ++e) part[e] = 0.f;
  for (int d = tid; d < D_DIM; d += 256) {
    float xv = x[d];
#pragma unroll
    for (int e = 0; e < NE; ++e) part[e] = fmaf(xv, Wg[e * D_DIM + d], part[e]);
  }
#pragma unroll
  for (int e = 0; e < NE; ++e) {
#pragma unroll
    for (int off = 32; off > 0; off >>= 1) part[e] += __shfl_down(part[e], off);
  }
  __shared__ float wsum[4][NE];
  const int wave = tid >> 6;
  if ((tid & 63) == 0) {
#pragma unroll
    for (int e = 0; e < NE; ++e) wsum[wave][e] = part[e];
  }
  __syncthreads();
  if (tid == 0) {
    float lg[NE];
#pragma unroll
    for (int e = 0; e < NE; ++e)
      lg[e] = wsum[0][e] + wsum[1][e] + wsum[2][e] + wsum[3][e] + bg[e];
    int e0 = 0;
#pragma unroll
    for (int e = 1; e < NE; ++e) if (lg[e] > lg[e0]) e0 = e;     // jax tie-break: lower idx
    int e1 = (e0 == 0) ? 1 : 0;
#pragma unroll
    for (int e = 0; e < NE; ++e) if (e != e0 && lg[e] > lg[e1]) e1 = e;
    // softmax denominator cancels in top-2 renormalization:
    float p1 = expf(lg[e1] - lg[e0]);            // p0 = 1
    float inv = 1.f / (1.f + p1);
    pairw[token * 2]     = inv;
    pairw[token * 2 + 1] = p1 * inv;
    int pos0 = atomicAdd(&cnt[e0], 1);
    bucket[e0 * CAP + pos0] = token * 2;
    int pos1 = atomicAdd(&cnt[e1], 1);
    bucket[e1 * CAP + pos1] = token * 2 + 1;
  }
}

// ---------------- tiny prefix sum over expert counts ------------------------
__global__ void prefix_kernel(const int* __restrict__ cnt, int* __restrict__ expoff)
{
  if (threadIdx.x == 0 && blockIdx.x == 0) {
    int s = 0;
#pragma unroll
    for (int e = 0; e < NE; ++e) { expoff[e] = s; s += cnt[e]; }
  }
}

// ---------------- fp32 -> bf16 of hidden states -----------------------------
__global__ __launch_bounds__(256) void convert_x_kernel(
    const float* __restrict__ X, unsigned short* __restrict__ Xb)
{
  const int i = blockIdx.x * 256 + threadIdx.x;
  const float4 v = ((const float4*)X)[i];
  short4v o;
  o.x = f2bf(v.x); o.y = f2bf(v.y); o.z = f2bf(v.z); o.w = f2bf(v.w);
  ((short4v*)Xb)[i] = o;
}

// ---------------- per-expert transpose fp32 [R][C] -> bf16 [C][R] -----------
__global__ __launch_bounds__(256) void transpose_bf16_kernel(
    const float* __restrict__ src, unsigned short* __restrict__ dst, int R, int C)
{
  __shared__ float tile[32][33];
  const int ez = blockIdx.z;
  src += (size_t)ez * R * C;
  dst += (size_t)ez * R * C;
  const int c0 = blockIdx.x * 32, r0 = blockIdx.y * 32;
  const int tx = threadIdx.x, ty = threadIdx.y;
#pragma unroll
  for (int i = ty; i < 32; i += 8)
    tile[i][tx] = src[(size_t)(r0 + i) * C + c0 + tx];
  __syncthreads();
#pragma unroll
  for (int i = ty; i < 32; i += 8)
    dst[(size_t)(c0 + i) * R + r0 + tx] = (unsigned short)f2bf(tile[tx][i]);
}

// ---------------- grouped expert GEMM, 256x256 tile -------------------------
// Counted-vmcnt 2-deep prefetch ring (T4, m139/m218 mechanism): loads for
// K-tile kt+1 stay in flight across the barrier; no vmcnt(0) in the main loop.
// LAYER 1: hmid[slot] = gelu(X[token] @ W1[e] + b1[e])   A = gathered token rows
// LAYER 2: out[token] += w * (hmid[slot] @ W2[e] + b2[e]) A = CONTIGUOUS slot rows
template<int LAYER>
__global__ __launch_bounds__(512, 2) void moe_gemm(
    const unsigned short* __restrict__ Abase,
    const unsigned short* __restrict__ Bt,
    const float* __restrict__ bias,
    const int* __restrict__ cnt,
    const int* __restrict__ expoff,
    const int* __restrict__ bucket,
    const float* __restrict__ pairw,
    unsigned short* __restrict__ hmid,
    float* __restrict__ out,
    int mt, int nt)
{
  constexpr int BM = 256, BN = 256, BK = 64;
  constexpr int KDIM = (LAYER == 1) ? D_DIM : F_DIM;
  constexpr int NDIM = (LAYER == 1) ? F_DIM : D_DIM;
  constexpr int KT = KDIM / BK;
  constexpr int SLOT = BM * BK * 2;          // 32 KiB per K-tile per operand

  // T1: bijective XCD chunk swizzle (nblk % 8 == 0), ntile fastest so the
  // chunk resident on one XCD reuses one A-tile + its expert's B-panels.
  const int nblk = mt * nt * NE;
  const int bid = blockIdx.x;
  const int v = (bid & 7) * (nblk >> 3) + (bid >> 3);
  const int e = v / (mt * nt);
  const int rem = v % (mt * nt);
  const int mtile = rem / nt;
  const int ntile = rem % nt;

  const int cnt_e = cnt[e];
  if (mtile * BM >= cnt_e) return;
  const int eoff = expoff[e];

  __shared__ __align__(16) char Alds[2][SLOT];   // 64 KiB
  __shared__ __align__(16) char Blds[2][SLOT];   // 64 KiB
  __shared__ int rowpair[BM];

  const int tid = threadIdx.x;
  const int lane = tid & 63;
  const int l15 = lane & 15, lhi = lane >> 4;
  const int wid = tid >> 6;
  const int wm = wid >> 2, wn = wid & 3;

  if (tid < BM) {
    int pos = mtile * BM + tid;
    rowpair[tid] = (pos < cnt_e) ? bucket[e * CAP + pos] : -1;
  }
  __syncthreads();

  // Staging plan: K-tile = 2048 chunks of 16 B; thread tid, load i owns chunk
  // ci = i*512 + tid -> LDS linear (global_load_lds dest). Source column is
  // pre-XOR-swizzled so swizzled ds_reads see the right data.
  const unsigned short* a_src[4];
  const unsigned short* b_src[4];
  int a_off[4], b_off[4];
#pragma unroll
  for (int i = 0; i < 4; ++i) {
    int ci = i * 512 + tid;
    int r = ci >> 3, c = ci & 7;
    int sc = c ^ (r & 7);                      // inverse swizzle on source
    size_t arow;
    if (LAYER == 1) {
      int pair = rowpair[r];
      arow = (pair < 0) ? 0 : (size_t)(pair >> 1);
    } else {
      arow = (size_t)(eoff + mtile * BM + r);  // contiguous slot rows
    }
    a_src[i] = Abase + arow * KDIM + sc * 8;
    a_off[i] = ci * 16;
    int ng = ntile * BN + r;
    b_src[i] = Bt + (size_t)e * NDIM * KDIM + (size_t)ng * KDIM + sc * 8;
    b_off[i] = ci * 16;
  }

  f32x4 acc[8][4];
#pragma unroll
  for (int m = 0; m < 8; ++m)
#pragma unroll
    for (int n = 0; n < 4; ++n) acc[m][n] = (f32x4){0.f, 0.f, 0.f, 0.f};

  // prologue: stage K-tiles 0 and 1 (16 loads in flight per wave)
#pragma unroll
  for (int i = 0; i < 4; ++i) gload_lds16(a_src[i], &Alds[0][0] + a_off[i]);
#pragma unroll
  for (int i = 0; i < 4; ++i) gload_lds16(b_src[i], &Blds[0][0] + b_off[i]);
#pragma unroll
  for (int i = 0; i < 4; ++i) gload_lds16(a_src[i] + BK, &Alds[1][0] + a_off[i]);
#pragma unroll
  for (int i = 0; i < 4; ++i) gload_lds16(b_src[i] + BK, &Blds[1][0] + b_off[i]);

  for (int kt = 0; kt < KT; ++kt) {
    const int b = kt & 1;
    // counted wait: K-tile kt complete; kt+1's 8 loads stay in flight
    if (kt + 1 < KT) asm volatile("s_waitcnt vmcnt(8)" ::: "memory");
    else             asm volatile("s_waitcnt vmcnt(0)" ::: "memory");
    __builtin_amdgcn_s_barrier();
    asm volatile("" ::: "memory");   // fence: no ds_read hoist above barrier

    // compute K-tile kt from buffer b (compiler inserts lgkmcnt for its loads)
#pragma unroll
    for (int kk = 0; kk < 2; ++kk) {
      const int c16 = kk * 4 + lhi;
      short8 bfr[4];
#pragma unroll
      for (int n = 0; n < 4; ++n) {
        int row = wn * 64 + n * 16 + l15;
        bfr[n] = *(const short8*)(&Blds[b][0] + row * 128 + ((c16 ^ (row & 7)) * 16));
      }
#pragma unroll
      for (int m = 0; m < 8; ++m) {
        int row = wm * 128 + m * 16 + l15;
        short8 af = *(const short8*)(&Alds[b][0] + row * 128 + ((c16 ^ (row & 7)) * 16));
#pragma unroll
        for (int n = 0; n < 4; ++n)
          acc[m][n] = __builtin_amdgcn_mfma_f32_16x16x32_bf16(af, bfr[n], acc[m][n], 0, 0, 0);
      }
    }

    asm volatile("" ::: "memory");   // fence: no ds_read sink below barrier
    __builtin_amdgcn_s_barrier();    // all waves done reading buffer b
    if (kt + 2 < KT) {               // restage buffer b with K-tile kt+2
#pragma unroll
      for (int i = 0; i < 4; ++i)
        gload_lds16(a_src[i] + (kt + 2) * BK, &Alds[b][0] + a_off[i]);
#pragma unroll
      for (int i = 0; i < 4; ++i)
        gload_lds16(b_src[i] + (kt + 2) * BK, &Blds[b][0] + b_off[i]);
    }
  }

  // epilogue: C/D layout col = lane&15, row = (lane>>4)*4 + j
#pragma unroll
  for (int m = 0; m < 8; ++m) {
#pragma unroll
    for (int j = 0; j < 4; ++j) {
      const int row = wm * 128 + m * 16 + lhi * 4 + j;
      const int pair = rowpair[row];
      if (pair < 0) continue;
#pragma unroll
      for (int n = 0; n < 4; ++n) {
        const int col = ntile * BN + wn * 64 + n * 16 + l15;
        float val = acc[m][n][j] + bias[e * NDIM + col];
        if (LAYER == 1) {
          float g = 0.5f * val * (1.f + erff(val * 0.70710678118654752f));
          hmid[(size_t)(eoff + mtile * BM + row) * F_DIM + col] =
              (unsigned short)f2bf(g);
        } else {
          float y = val * pairw[pair];
          atomicAdd(out + ((size_t)(pair >> 1) * D_DIM + col), y);
        }
      }
    }
  }
}

// ---------------- launch ----------------------------------------------------
extern "C" void kernel_launch(void* const* d_in, const int* in_sizes, int n_in,
                              void* d_out, int out_size, void* d_ws, size_t ws_size,
                              hipStream_t stream)
{
  const float* X  = (const float*)d_in[0];
  const float* Wg = (const float*)d_in[1];
  const float* bg = (const float*)d_in[2];
  const float* W1 = (const float*)d_in[3];
  const float* b1 = (const float*)d_in[4];
  const float* W2 = (const float*)d_in[5];
  const float* b2 = (const float*)d_in[6];
  float* out = (float*)d_out;

  char* ws = (char*)d_ws;
  size_t off = 0;
  auto alloc = [&](size_t sz) {
    size_t o = off;
    off = (off + sz + 255) & ~(size_t)255;
    return o;
  };
  int*            cnt    = (int*)(ws + alloc(NE * sizeof(int)));
  int*            expoff = (int*)(ws + alloc(NE * sizeof(int)));
  int*            bucket = (int*)(ws + alloc((size_t)NE * CAP * sizeof(int)));
  float*          pairw  = (float*)(ws + alloc((size_t)N_TOK * 2 * sizeof(float)));
  unsigned short* Xb     = (unsigned short*)(ws + alloc((size_t)N_TOK * D_DIM * 2));
  unsigned short* W1t    = (unsigned short*)(ws + alloc((size_t)NE * D_DIM * F_DIM * 2));
  unsigned short* W2t    = (unsigned short*)(ws + alloc((size_t)NE * D_DIM * F_DIM * 2));
  unsigned short* hmid   = (unsigned short*)(ws + alloc((size_t)(N_TOK * 2 + 256) * F_DIM * 2));

  hipMemsetAsync(cnt, 0, NE * sizeof(int), stream);
  hipMemsetAsync(out, 0, (size_t)out_size * sizeof(float), stream);

  convert_x_kernel<<<N_TOK * D_DIM / 4 / 256, 256, 0, stream>>>(X, Xb);
  transpose_bf16_kernel<<<dim3(F_DIM / 32, D_DIM / 32, NE), dim3(32, 8), 0, stream>>>(
      W1, W1t, D_DIM, F_DIM);
  transpose_bf16_kernel<<<dim3(D_DIM / 32, F_DIM / 32, NE), dim3(32, 8), 0, stream>>>(
      W2, W2t, F_DIM, D_DIM);
  gate_kernel<<<N_TOK, 256, 0, stream>>>(X, Wg, bg, cnt, bucket, pairw);
  prefix_kernel<<<1, 64, 0, stream>>>(cnt, expoff);

  const int mt = N_TOK / 256;
  const int nt1 = F_DIM / 256, nt2 = D_DIM / 256;
  moe_gemm<1><<<nt1 * mt * NE, 512, 0, stream>>>(
      Xb, W1t, b1, cnt, expoff, bucket, pairw, hmid, out, mt, nt1);
  moe_gemm<2><<<nt2 * mt * NE, 512, 0, stream>>>(
      hmid, W2t, b2, cnt, expoff, bucket, pairw, hmid, out, mt, nt2);
}